// Round 14
// baseline (147.337 us; speedup 1.0000x reference)
//
#include <hip/hip_runtime.h>
#include <hip/hip_fp16.h>
#include <math.h>

// ---------------- problem constants ----------------
// x: (16, 2048, 64) f32  -> out: (16, 2048, 64, 5) f32
// scales = {1,27,76,167,336}; morlet int_psi, n=1024, [-8,8]
#define NB    16
#define T     2048
#define NC    64
#define NROWS (NB*NC)     // 1024
#define PADL2 2696        // left zero-pad (halves)
#define XSH_N 7440        // 2696 + 2048 + right pad (logical halves)

// 32-diagonal Toeplitz W (for 32x32x16 MFMA), 16-halves chunk axis c16:
// Out[32A'+b'] = sum_k' W32[b'][k'-16*CLO16] * xsh[32A'+k'], k' = b'+i+posoff.
//   sl:      0      1      2      3      4
//   scale:   336    167    76     27     1
//   CLO16:   0      84     130    154    167
//   KS16:    5424   2720   1264   480    64     (row stride, halves)
//   WOFF32:  0      173568 260608 301056 316416 (total 318464 halves = 622KB)
//   outslot: 4      3      2      1      0
// alive (nested): [0,84)N1 [84,130)N2 [130,154)N3 [154,167)N4 [167,171)N5
//                 [171,184)N4 [184,209)N3 [209,254)N2 [254,339)N1
// k-split: wp0 = [0,171) (320 u), wp1 = [171,339) (302 u) — disjoint A traffic.
// Layout VERIFIED on HW (rounds 11/12, absmax 0.0625).

// LDS xsh swizzle (round-12 lesson: 32-half lane stride = 16-way bank conflict,
// SQ_LDS_BANK_CONFLICT 9.56M ~ 15us/CU): physical 16B-unit PU(u) = u + (u>>5).
// Lanes' PU%8 classes -> exactly 4 lanes each = b128 structural floor. Injective.
#define PU(u) ((u) + ((u) >> 5))
#define XSH_UNITS 930          // XSH_N/8 logical units per row
#define XSH_PHYSH 7808         // 976 physical units * 8 halves (PU(939)=968 max read)

// ws layout (bytes):
//   0        : __half W32[318464]                  (622 KB, region 640 KB)
//   640 KB   : __half xT[1024][2048]               (4 MB)
//   640KB+4MB: __half outT2[16][128][64][5][16]    (20 MB)  [n][tb][c][s][tt]
#define WS_XT    655360u
#define WS_OUTT  4849664u

typedef _Float16 half8  __attribute__((ext_vector_type(8)));
typedef _Float16 half4v __attribute__((ext_vector_type(4)));
typedef float    f32x16 __attribute__((ext_vector_type(16)));

// ---------------- kernel 1: W32-build (blocks 0..31) + transpose (32..159) ----------------
// [verified rounds 11/12]
__global__ __launch_bounds__(1024) void cwt_prep(const float* __restrict__ x,
                                                 __half* __restrict__ xT,
                                                 __half* __restrict__ W) {
    __shared__ double ps[1024];
    __shared__ double sc[1024];
    __shared__ float  k32[1024];
    __shared__ float  tile4[4][64 * 65];
    const int tid = threadIdx.x;

    if (blockIdx.x < 32) {
        const int bb = blockIdx.x;                // diagonal b' in [0,32)
        constexpr int SCe[5]    = {336, 167, 76, 27, 1};
        constexpr int KS16[5]   = {5424, 2720, 1264, 480, 64};
        constexpr int WOFF32[5] = {0, 173568, 260608, 301056, 316416};
        constexpr int CLO16[5]  = {0, 84, 130, 154, 167};

        // zero-fill own rows only
        {
            const uint4 z = make_uint4(0u, 0u, 0u, 0u);
            #pragma unroll
            for (int sl = 0; sl < 5; ++sl) {
                uint4* z4 = (uint4*)(W + WOFF32[sl] + bb * KS16[sl]);
                const int n8 = KS16[sl] / 8;
                for (int i = tid; i < n8; i += 1024) z4[i] = z;
            }
        }

        const double delta = 16.0 / 1023.0;
        double t = (tid == 1023) ? 8.0 : (-8.0 + delta * (double)tid);
        {
            const float tf = (float)t;
            ps[tid] = (double)(expf(-0.5f * tf * tf) * cosf(5.0f * tf));
        }
        __syncthreads();   // also orders the zero-fill before the scatter below

        double* a = ps; double* b = sc;
        for (int off = 1; off < 1024; off <<= 1) {
            double v = a[tid];
            if (tid >= off) v += a[tid - off];
            b[tid] = v;
            __syncthreads();
            double* tmp = a; a = b; b = tmp;
        }
        const double step = ((-8.0 + delta) + 8.0);   // NOT exactly 16/1023
        k32[tid] = (float)(a[tid] * step);
        __syncthreads();

        for (int sl = 0; sl < 5; ++sl) {
            const int s = SCe[sl];
            const int L = 16 * s + 1;
            const double c = (double)s * step;
            const float sq = (float)sqrt((double)s);
            const int posoff = PADL2 - 8 * s - 1;
            const int kb0 = posoff - 16 * CLO16[sl];
            __half* wb = W + WOFF32[sl] + bb * KS16[sl];
            for (int i = tid; i <= L; i += 1024) {
                float g; bool wr = true;
                if (i == 0) {
                    g = sq * k32[0];
                } else if (i == L) {
                    long long jl = (long long)((double)(L - 1) / c);
                    if (jl > 1023) jl = 1023;
                    g = -sq * k32[jl];
                } else {
                    long long j1 = (long long)((double)i / c);
                    long long j0 = (long long)((double)(i - 1) / c);
                    if (j1 > 1023) j1 = 1023;
                    if (j0 > 1023) j0 = 1023;
                    wr = (j1 > j0);
                    g = sq * (k32[j1] - k32[j0]);
                }
                if (wr) {
                    wb[kb0 + i + bb] = __float2half(g);
                }
            }
        }
    } else {
        const int g    = tid >> 8;                // 0..3: tile within block
        const int t256 = tid & 255;
        const int ti   = (blockIdx.x - 32) * 4 + g;  // 0..511
        const int n    = ti >> 5;
        const int t0   = (ti & 31) << 6;
        float* tl = tile4[g];

        const float4* src = (const float4*)(x + ((size_t)(n * T + t0)) * NC);
        #pragma unroll
        for (int k = 0; k < 4; ++k) {
            float4 v = src[t256 + 256 * k];
            const int flat = (t256 + 256 * k) * 4;
            const int tt = flat >> 6, c = flat & 63;
            tl[tt * 65 + c + 0] = v.x;
            tl[tt * 65 + c + 1] = v.y;
            tl[tt * 65 + c + 2] = v.z;
            tl[tt * 65 + c + 3] = v.w;
        }
        __syncthreads();
        const int lane = t256 & 63, w4 = t256 >> 6;
        for (int cc = w4; cc < 64; cc += 4) {
            xT[((size_t)(n * 64 + cc)) * T + t0 + lane] = __float2half(tl[lane * 65 + cc]);
        }
    }
}

// ---------------- kernel 2: 32x32x16 conv, 2 rows/wave, swizzled LDS, k-split ----------------
// 4 waves/block: wh = col half of A'-groups, wp = chunk half. wp1 partials for
// sl0..3 x 2 rows reduced into wp0 via stride-17 f32 LDS (R9-verified pattern).
// Per wave: ~311 A-loads (1:2 vs MFMA), ~340 swizzled ds_read_b128, 622 MFMAs.
template<int N, int DEPTH>
__device__ __forceinline__ void conv_seg(int c0, int c1, int blu,
                                         const _Float16* __restrict__ xs0,
                                         const _Float16* __restrict__ xs1,
                                         const _Float16* const (&ap)[5],
                                         f32x16 (&acc)[5][2]) {
    half8 A[DEPTH][N];
    half8 B0[DEPTH], B1[DEPTH];
    #pragma unroll
    for (int d = 0; d < DEPTH; ++d) {
        const int ko = (c0 + d) << 4;
        #pragma unroll
        for (int sl = 0; sl < N; ++sl) A[d][sl] = *(const half8*)(ap[sl] + ko);
        const int lu = blu + 2 * (c0 + d);
        B0[d] = *(const half8*)(xs0 + 8 * PU(lu));
        B1[d] = *(const half8*)(xs1 + 8 * PU(lu));
    }
    int c = c0;
    for (; c + DEPTH <= c1; c += DEPTH) {
        #pragma unroll
        for (int d = 0; d < DEPTH; ++d) {
            #pragma unroll
            for (int sl = 0; sl < N; ++sl) {
                acc[sl][0] = __builtin_amdgcn_mfma_f32_32x32x16_f16(A[d][sl], B0[d], acc[sl][0], 0, 0, 0);
                acc[sl][1] = __builtin_amdgcn_mfma_f32_32x32x16_f16(A[d][sl], B1[d], acc[sl][1], 0, 0, 0);
            }
            const int ko = (c + DEPTH + d) << 4;   // prefetch (unclamped, memory-safe:
            #pragma unroll                         // stays inside W region / xsh phys)
            for (int sl = 0; sl < N; ++sl) A[d][sl] = *(const half8*)(ap[sl] + ko);
            const int lu = blu + 2 * (c + DEPTH + d);
            B0[d] = *(const half8*)(xs0 + 8 * PU(lu));
            B1[d] = *(const half8*)(xs1 + 8 * PU(lu));
        }
    }
    #pragma unroll
    for (int d = 0; d < DEPTH; ++d) {
        if (d < c1 - c) {
            #pragma unroll
            for (int sl = 0; sl < N; ++sl) {
                acc[sl][0] = __builtin_amdgcn_mfma_f32_32x32x16_f16(A[d][sl], B0[d], acc[sl][0], 0, 0, 0);
                acc[sl][1] = __builtin_amdgcn_mfma_f32_32x32x16_f16(A[d][sl], B1[d], acc[sl][1], 0, 0, 0);
            }
        }
    }
}

__global__ __launch_bounds__(256, 2) void cwt_conv_mfma(const __half* __restrict__ xT,
                                                        const __half* __restrict__ Wg,
                                                        __half* __restrict__ outT) {
    constexpr int KS16[5]   = {5424, 2720, 1264, 480, 64};
    constexpr int WOFF32[5] = {0, 173568, 260608, 301056, 316416};
    constexpr int CLO16[5]  = {0, 84, 130, 154, 167};
    constexpr int OS[5]     = {4, 3, 2, 1, 0};

    __shared__ _Float16 xsh[2][XSH_PHYSH];        // 31232 B (swizzled units)
    __shared__ _Float16 ostage[2048];             // 4096 B (1024 per wh-wave)
    __shared__ float    red[2][2][1088];          // 17408 B reduction buffer
    const int tid  = threadIdx.x;
    const int rp   = blockIdx.x;                  // row pair: rows 2rp, 2rp+1
    const int lane = tid & 63;
    const int wv   = tid >> 6;                    // wave 0..3
    const int wh   = wv & 1;                      // col half: A'-groups [32wh, 32wh+32)
    const int wp   = wv >> 1;                     // chunk half: [0,171) / [171,339)
    const int col  = lane & 31;                   // A: W32 row b'; B/D: col (A'-group)
    const int kh   = lane >> 5;                   // k-half within 16k window

    // ---- stage both rows through the PU swizzle (every logical unit written) ----
    {
        const uint4 z = make_uint4(0u, 0u, 0u, 0u);
        for (int ii = tid; ii < 2 * XSH_UNITS; ii += 256) {
            const int rr = (ii >= XSH_UNITS) ? 1 : 0;
            const int i  = ii - XSH_UNITS * rr;   // logical unit in row rr
            uint4 v = z;
            if (i >= PADL2 / 8 && i < (PADL2 + T) / 8)
                v = ((const uint4*)(xT + (size_t)(2 * rp + rr) * T))[i - PADL2 / 8];
            ((uint4*)xsh[rr])[PU(i)] = v;
        }
    }
    __syncthreads();

    // per-lane bases
    const int blu = 128 * wh + 4 * col + kh;      // logical B unit at chunk 0
    const _Float16* ap[5];
    #pragma unroll
    for (int sl = 0; sl < 5; ++sl)
        ap[sl] = (const _Float16*)Wg + WOFF32[sl] + col * KS16[sl] + 8 * kh
                 - 16 * CLO16[sl];

    f32x16 acc[5][2];
    #pragma unroll
    for (int sl = 0; sl < 5; ++sl)
        #pragma unroll
        for (int rr = 0; rr < 2; ++rr)
            #pragma unroll
            for (int r = 0; r < 16; ++r) acc[sl][rr][r] = 0.f;

    // nested alive segments, split by wp (disjoint chunks, disjoint A traffic)
    if (wp == 0) {
        conv_seg<1,4>(  0,  84, blu, xsh[0], xsh[1], ap, acc);
        conv_seg<2,3>( 84, 130, blu, xsh[0], xsh[1], ap, acc);
        conv_seg<3,2>(130, 154, blu, xsh[0], xsh[1], ap, acc);
        conv_seg<4,2>(154, 167, blu, xsh[0], xsh[1], ap, acc);
        conv_seg<5,1>(167, 171, blu, xsh[0], xsh[1], ap, acc);
    } else {
        conv_seg<4,2>(171, 184, blu, xsh[0], xsh[1], ap, acc);
        conv_seg<3,2>(184, 209, blu, xsh[0], xsh[1], ap, acc);
        conv_seg<2,3>(209, 254, blu, xsh[0], xsh[1], ap, acc);
        conv_seg<1,4>(254, 339, blu, xsh[0], xsh[1], ap, acc);
    }

    // ---- cross-pair reduction: wp1 -> wp0 for (sl 0..3) x (rr 0..1), 4 rounds ----
    // sl4 (scale 1) lives entirely in wp0's [167,171): no reduction needed.
    __syncthreads();
    #pragma unroll
    for (int rnd = 0; rnd < 4; ++rnd) {
        if (wp == 1) {
            #pragma unroll
            for (int j = 0; j < 2; ++j) {
                const int s2 = rnd * 2 + j, sl = s2 >> 1, rr = s2 & 1;
                #pragma unroll
                for (int r = 0; r < 16; ++r)
                    red[j][wh][lane * 17 + r] = acc[sl][rr][r];
            }
        }
        __syncthreads();
        if (wp == 0) {
            #pragma unroll
            for (int j = 0; j < 2; ++j) {
                const int s2 = rnd * 2 + j, sl = s2 >> 1, rr = s2 & 1;
                #pragma unroll
                for (int r = 0; r < 16; ++r)
                    acc[sl][rr][r] += red[j][wh][lane * 17 + r];
            }
        }
        __syncthreads();
    }

    // ---- epilogue (wp0 waves): verified r11/r12 mapping, per row ----
    if (wp == 0) {
        _Float16* os = ostage + 1024 * wh;        // wave-local
        #pragma unroll
        for (int rr = 0; rr < 2; ++rr) {
            const int row  = 2 * rp + rr;
            const int nidx = row >> 6;
            const int cidx = row & 63;
            #pragma unroll
            for (int sl = 0; sl < 5; ++sl) {
                #pragma unroll
                for (int rq = 0; rq < 4; ++rq) {  // b' = (r&3) + 8*rq + 4*kh
                    half4v hv;
                    #pragma unroll
                    for (int r = 0; r < 4; ++r) hv[r] = (_Float16)acc[sl][rr][4 * rq + r];
                    *(half4v*)(os + 32 * col + 8 * rq + 4 * kh) = hv;
                }
                half8 o0 = *(const half8*)(os + 16 * lane);
                half8 o1 = *(const half8*)(os + 16 * lane + 8);
                __half* ob = outT + ((size_t)(((nidx * 128 + 64 * wh + lane) * 64 + cidx) * 5 + OS[sl])) * 16;
                *(half8*)(ob)     = o0;
                *(half8*)(ob + 8) = o1;
            }
        }
    }
}

// ---------------- kernel 3: outT2[n][tb][c][s][16] -> out[n][t][c][s] ----------------
__global__ __launch_bounds__(256) void cwt_fix(const __half* __restrict__ outT,
                                               float* __restrict__ out) {
    __shared__ float tile[16 * 320];              // [tt][c*5+s]
    const int b  = blockIdx.x;                    // 0..2047
    const int n  = b >> 7;
    const int tb = b & 127;
    const int tid = threadIdx.x;

    const uint4* src = (const uint4*)(outT + (size_t)(n * 128 + tb) * 5120);
    for (int i = tid; i < 640; i += 256) {
        uint4 v = src[i];                         // 8 halves: (c,s) fixed, tt0..tt0+7
        const __half* h = (const __half*)&v;
        const int h0  = i * 8;
        const int sg  = h0 >> 4;                  // c*5+s
        const int tt0 = h0 & 15;                  // 0 or 8
        #pragma unroll
        for (int k = 0; k < 8; ++k) tile[(tt0 + k) * 320 + sg] = __half2float(h[k]);
    }
    __syncthreads();
    float4* dst = (float4*)(out + (size_t)(n * 2048 + tb * 16) * 320);
    const float4* tl = (const float4*)tile;
    for (int k = tid; k < 1280; k += 256) dst[k] = tl[k];
}

// ---------------- launch ----------------
extern "C" void kernel_launch(void* const* d_in, const int* in_sizes, int n_in,
                              void* d_out, int out_size, void* d_ws, size_t ws_size,
                              hipStream_t stream) {
    const float* x = (const float*)d_in[0];
    float* out = (float*)d_out;
    char* ws = (char*)d_ws;

    __half* W    = (__half*)ws;
    __half* xT   = (__half*)(ws + WS_XT);
    __half* outT = (__half*)(ws + WS_OUTT);

    cwt_prep<<<160, 1024, 0, stream>>>(x, xT, W);
    cwt_conv_mfma<<<NROWS / 2, 256, 0, stream>>>(xT, W, outT);
    cwt_fix<<<2048, 256, 0, stream>>>(outT, out);
}